// Round 11
// baseline (463.732 us; speedup 1.0000x reference)
//
#include <hip/hip_runtime.h>

#define BB 8
#define NN 2048
#define LL 1280
#define HH 160
#define BN (BB*NN)          // 16384
#define NO (2*HH + LL)      // 1600
#define SHIFT 40.0f

typedef __attribute__((ext_vector_type(8))) short short8;
typedef __attribute__((ext_vector_type(4))) float floatx4;

__device__ __forceinline__ unsigned short f2bf(float f) {
    unsigned int u = __builtin_bit_cast(unsigned int, f);
    u = (u + 0x7FFFu + ((u >> 16) & 1u)) >> 16;
    return (unsigned short)u;
}
__device__ __forceinline__ float bf2f(unsigned short h) {
    unsigned int u = ((unsigned int)h) << 16;
    return __builtin_bit_cast(float, u);
}
__device__ __forceinline__ void split2(float f, unsigned short& hi, unsigned short& lo) {
    hi = f2bf(f);
    lo = f2bf(f - bf2f(hi));
}

// Fragment-major layouts (MFMA-native, lane = ((k>>3)&3)*16 + (row&15)):
//   q/k:  F(m,h)   = (m>>4)*2560  + (h>>5)*512   + ((h>>3)&3)*128 + (m&15)*8 + (h&7)
//   P:    F(r,tok) = (r>>4)*32768 + (tok>>5)*512 + ((tok>>3)&3)*128 + (r&15)*8 + (tok&7)
//   vt:   F(f,tok) = (f>>4)*32768 + (tok>>5)*512 + ((tok>>3)&3)*128 + (f&15)*8 + (tok&7)
//   xh/xl:F(m,k)   = (m>>4)*20480 + (k>>5)*512   + ((k>>3)&3)*128 + (m&15)*8 + (k&7)
//   wv:   F(f,k)   = (f>>4)*20480 + (k>>5)*512   + ((k>>3)&3)*128 + (f&15)*8 + (k&7)
//   wqk:  F(o,k)   = (o>>4)*20480 + (k>>5)*512   + ((k>>3)&3)*128 + (o&15)*8 + (k&7)
// A 16-row x 32-k fragment = one contiguous 1KB wave-load / gload_lds chunk.

__device__ __forceinline__ void gl16(const unsigned short* g, unsigned short* l) {
    __builtin_amdgcn_global_load_lds(
        (const __attribute__((address_space(1))) unsigned int*)g,
        (__attribute__((address_space(3))) unsigned int*)l, 16, 0, 0);
}

// ---------------- cast weights (wqk + wv frag-major) ----------------
__global__ __launch_bounds__(256) void cast_w(
    const float* __restrict__ Wq, const float* __restrict__ Wk, const float* __restrict__ Wv,
    unsigned short* __restrict__ wqk_h, unsigned short* __restrict__ wqk_l,
    unsigned short* __restrict__ wv)
{
    int o = blockIdx.x;   // 0..1599
    if (o < 2*HH) {
        const float* src = (o < HH) ? (Wq + (size_t)o * LL) : (Wk + (size_t)(o - HH) * LL);
        unsigned short* dh = wqk_h + (size_t)(o >> 4) * 20480 + (o & 15) * 8;
        unsigned short* dl = wqk_l + (size_t)(o >> 4) * 20480 + (o & 15) * 8;
        for (int c = threadIdx.x; c < LL; c += 256) {
            unsigned short h, l;
            split2(src[c], h, l);
            unsigned off = (unsigned)(c >> 5) * 512 + ((c >> 3) & 3) * 128 + (c & 7);
            dh[off] = h; dl[off] = l;
        }
    } else {
        // wv frag-major
        int f = o - 2*HH;
        const float* src = Wv + (size_t)f * LL;
        unsigned short* dstF = wv + (size_t)(f >> 4) * 20480 + (f & 15) * 8;
        for (int c = threadIdx.x * 4; c < LL; c += 256 * 4) {
            float4 v = *(const float4*)(src + c);
            ushort4 u;
            u.x = f2bf(v.x); u.y = f2bf(v.y); u.z = f2bf(v.z); u.w = f2bf(v.w);
            *(ushort4*)(dstF + (size_t)(c >> 5) * 512 + ((c >> 3) & 3) * 128 + (c & 7)) = u;
        }
    }
}

// ---------------- cast x -> bf16x2 (hi+lo) frag-major ----------------
__global__ __launch_bounds__(256) void cast_x(
    const float* __restrict__ x,
    unsigned short* __restrict__ xh, unsigned short* __restrict__ xl)
{
    const int g   = blockIdx.x;              // m16 group 0..1023
    const int tid = threadIdx.x;
    const float* src = x + (size_t)(g * 16 + (tid & 15)) * LL + ((tid >> 4) & 3) * 8;
    unsigned short* dsth = xh + (size_t)g * 20480 + tid * 8;
    unsigned short* dstl = xl + (size_t)g * 20480 + tid * 8;
    const int ks0 = tid >> 6;                // 0..3
    #pragma unroll
    for (int it = 0; it < 10; it++) {
        int k0 = (it * 4 + ks0) * 32;
        float4 f0 = *(const float4*)(src + k0);
        float4 f1 = *(const float4*)(src + k0 + 4);
        float fv[8] = {f0.x, f0.y, f0.z, f0.w, f1.x, f1.y, f1.z, f1.w};
        short8 h8, l8;
        #pragma unroll
        for (int i = 0; i < 8; i++) {
            unsigned short hh, lll;
            split2(fv[i], hh, lll);
            h8[i] = (short)hh; l8[i] = (short)lll;
        }
        *(short8*)(dsth + it * 2048) = h8;
        *(short8*)(dstl + it * 2048) = l8;
    }
}

// ---------------- Kernel 1a v3: q,k projection, direct-frag stream ----------------
__global__ __launch_bounds__(256, 2) void proj_qk(
    const unsigned short* __restrict__ xh, const unsigned short* __restrict__ xl,
    const unsigned short* __restrict__ wh, const unsigned short* __restrict__ wl,
    const float* __restrict__ bq, const float* __restrict__ bk,
    unsigned short* __restrict__ qh, unsigned short* __restrict__ ql,
    unsigned short* __restrict__ kh, unsigned short* __restrict__ kl)
{
    const int mg0 = blockIdx.x * 2;       // m16 group base (32 rows)
    const int tid = threadIdx.x;
    const int wave = tid >> 6, lane = tid & 63;
    const int l15 = lane & 15, l4 = lane >> 4;

    const unsigned aBase = (unsigned)mg0 * 20480u + lane * 8;
    const unsigned bBase = (unsigned)(wave * 5) * 20480u + lane * 8;

    floatx4 acc[2][5] = {};

    #pragma unroll 2
    for (int ks = 0; ks < 40; ks++) {
        const unsigned ko = (unsigned)ks * 512u;
        short8 ah[2], al[2], bh[5], bl[5];
        #pragma unroll
        for (int mf = 0; mf < 2; mf++) {
            ah[mf] = *(const short8*)(xh + aBase + mf * 20480u + ko);
            al[mf] = *(const short8*)(xl + aBase + mf * 20480u + ko);
        }
        #pragma unroll
        for (int nf = 0; nf < 5; nf++) {
            bh[nf] = *(const short8*)(wh + bBase + nf * 20480u + ko);
            bl[nf] = *(const short8*)(wl + bBase + nf * 20480u + ko);
        }
        #pragma unroll
        for (int mf = 0; mf < 2; mf++)
            #pragma unroll
            for (int nf = 0; nf < 5; nf++) {
                acc[mf][nf] = __builtin_amdgcn_mfma_f32_16x16x32_bf16(ah[mf], bh[nf], acc[mf][nf], 0, 0, 0);
                acc[mf][nf] = __builtin_amdgcn_mfma_f32_16x16x32_bf16(al[mf], bh[nf], acc[mf][nf], 0, 0, 0);
                acc[mf][nf] = __builtin_amdgcn_mfma_f32_16x16x32_bf16(ah[mf], bl[nf], acc[mf][nf], 0, 0, 0);
            }
    }

    // epilogue: bias + bf16x2 split + frag-major q/k stores
    #pragma unroll
    for (int nf = 0; nf < 5; nf++) {
        int o = wave * 80 + nf * 16 + l15;
        bool isQ = (o < HH);
        float bias = isQ ? bq[o] : bk[o - HH];
        int oo = isQ ? o : (o - HH);
        unsigned short* dh = isQ ? qh : kh;
        unsigned short* dl = isQ ? ql : kl;
        unsigned ob = (unsigned)(oo >> 5) * 512u + ((oo >> 3) & 3) * 128u + (oo & 7);
        #pragma unroll
        for (int mf = 0; mf < 2; mf++) {
            unsigned fa0 = (unsigned)(mg0 + mf) * 2560u + ob + (l4 * 4) * 8u;
            #pragma unroll
            for (int r = 0; r < 4; r++) {
                float val = acc[mf][nf][r] + bias;
                unsigned short vh, vl;
                split2(val, vh, vl);
                dh[fa0 + r * 8] = vh;
                dl[fa0 + r * 8] = vl;
            }
        }
    }
}

// ---------------- Kernel 1b v2: v projection, v7 quadrant pipeline ----------------
__global__ __launch_bounds__(256, 3) void proj_v(
    const unsigned short* __restrict__ xh, const unsigned short* __restrict__ wv,
    const float* __restrict__ bv, unsigned short* __restrict__ vt)
{
    __shared__ __align__(16) unsigned short Sm[3 * 8192];   // 48 KiB

    const int bid = blockIdx.x;         // 0..1279
    const int xcd = bid & 7;
    const int q   = bid >> 3;           // 0..159
    const int mt  = xcd * 16 + q / 10;  // m-tile 0..127 (batch = xcd)
    const int ft  = q % 10;             // f-tile 0..9
    const int m0 = mt * 128;
    const int f0 = ft * 128;

    const int tid = threadIdx.x;
    const int wave = tid >> 6, lane = tid & 63;
    const int l15 = lane & 15, l4 = lane >> 4;
    const int wm = wave >> 1, wn = wave & 1;

    const unsigned short* AF = xh + (size_t)(m0 >> 4) * 20480;
    const unsigned short* BF = wv + (size_t)(f0 >> 4) * 20480;

    const int sp0 = tid, sp1 = 256 + tid;
    const unsigned sa0 = (unsigned)(sp0 >> 6) * 20480u + (sp0 & 63) * 8;
    const unsigned sa1 = (unsigned)(sp1 >> 6) * 20480u + (sp1 & 63) * 8;

    floatx4 acc[4][4] = {};

    auto STAGE = [&](int slot, int ks) {
        unsigned short* A  = Sm + slot * 8192;
        unsigned short* Bs = A + 4096;
        const unsigned ko = (unsigned)ks * 512u;
        gl16(AF + sa0 + ko, A  + sp0 * 8);
        gl16(BF + sa0 + ko, Bs + sp0 * 8);
        gl16(AF + sa1 + ko, A  + sp1 * 8);
        gl16(BF + sa1 + ko, Bs + sp1 * 8);
    };

    auto COMPUTE = [&](int slot) {
        const unsigned short* A  = Sm + slot * 8192;
        const unsigned short* Bs = A + 4096;
        short8 a[4], bb[4];
        #pragma unroll
        for (int mf = 0; mf < 4; mf++)
            a[mf] = *(const short8*)(A + ((wm * 4 + mf) * 64 + lane) * 8);
        #pragma unroll
        for (int nf = 0; nf < 4; nf++)
            bb[nf] = *(const short8*)(Bs + ((wn * 4 + nf) * 64 + lane) * 8);
        __builtin_amdgcn_s_setprio(1);
        #pragma unroll
        for (int mf = 0; mf < 4; mf++)
            #pragma unroll
            for (int nf = 0; nf < 4; nf++)
                acc[mf][nf] = __builtin_amdgcn_mfma_f32_16x16x32_bf16(a[mf], bb[nf], acc[mf][nf], 0, 0, 0);
        __builtin_amdgcn_s_setprio(0);
    };

    STAGE(0, 0); STAGE(1, 1); STAGE(2, 2);

    int s = 0;
    for (int kt = 0; kt < 37; ++kt) {              // 40 K-steps total
        asm volatile("s_waitcnt vmcnt(8)" ::: "memory");
        asm volatile("s_barrier" ::: "memory");
        COMPUTE(s);
        asm volatile("s_barrier" ::: "memory");
        STAGE(s, kt + 3);
        s = (s == 2) ? 0 : s + 1;
    }
    asm volatile("s_waitcnt vmcnt(8)" ::: "memory");
    asm volatile("s_barrier" ::: "memory");
    COMPUTE(s); s = (s == 2) ? 0 : s + 1;
    asm volatile("s_waitcnt vmcnt(4)" ::: "memory");
    asm volatile("s_barrier" ::: "memory");
    COMPUTE(s); s = (s == 2) ? 0 : s + 1;
    asm volatile("s_waitcnt vmcnt(0)" ::: "memory");
    asm volatile("s_barrier" ::: "memory");
    COMPUTE(s);

    // epilogue: bias + direct frag-major vt stores (ushort4 over r)
    const int b    = m0 >> 11;                    // == xcd
    const int tokb = (m0 & 2047) + wm * 64;
    unsigned short* vtB = vt + (size_t)b * LL * NN;
    float bvv[4];
    #pragma unroll
    for (int nf = 0; nf < 4; nf++)
        bvv[nf] = bv[f0 + wn * 64 + nf * 16 + l15];

    #pragma unroll
    for (int mf = 0; mf < 4; mf++)
        #pragma unroll
        for (int nf = 0; nf < 4; nf++) {
            int f   = f0 + wn * 64 + nf * 16 + l15;
            int tok = tokb + mf * 16 + l4 * 4;    // +r, r=0..3 contiguous in (tok&7)
            ushort4 u;
            u.x = f2bf(acc[mf][nf][0] + bvv[nf]);
            u.y = f2bf(acc[mf][nf][1] + bvv[nf]);
            u.z = f2bf(acc[mf][nf][2] + bvv[nf]);
            u.w = f2bf(acc[mf][nf][3] + bvv[nf]);
            *(ushort4*)(vtB + (size_t)(f >> 4) * 32768 + (tok >> 5) * 512
                        + ((tok >> 3) & 3) * 128 + (f & 15) * 8 + (tok & 7)) = u;
        }
}

// ---------------- Kernel 2a: S = exp(QK^T - SHIFT) -> frag-major P ----------------
__global__ __launch_bounds__(256, 2) void s_exp(
    const unsigned short* __restrict__ qhp, const unsigned short* __restrict__ qlp,
    const unsigned short* __restrict__ khp, const unsigned short* __restrict__ klp,
    unsigned short* __restrict__ P, float* __restrict__ Lsum)
{
    __shared__ float sums[4][32];
    const int b  = blockIdx.y;
    const int i0 = blockIdx.x * 32;
    const int tid = threadIdx.x;
    const int wave = tid >> 6, lane = tid & 63;
    const int l15 = lane & 15, l4 = lane >> 4;

    // resident A-frags: coalesced frag-major loads
    short8 aqh[2][5], aql[2][5];
    #pragma unroll
    for (int rt = 0; rt < 2; rt++) {
        const size_t rowb = (size_t)((b * NN + i0 + rt * 16) >> 4) * 2560 + lane * 8;
        #pragma unroll
        for (int ks = 0; ks < 5; ks++) {
            aqh[rt][ks] = *(const short8*)&qhp[rowb + ks * 512];
            aql[rt][ks] = *(const short8*)&qlp[rowb + ks * 512];
        }
    }

    float sr[2][4] = {};
    unsigned short* Pb = P + (size_t)b * NN * NN + (size_t)(i0 >> 4) * 32768;

    for (int c0 = 0; c0 < NN; c0 += 256) {
        const int jb = c0 + wave * 64;      // wave's 64-col stripe
        #pragma unroll
        for (int ct = 0; ct < 4; ct++) {
            const int tok0 = jb + ct * 16;                 // multiple of 16
            const int tok  = tok0 + l15;
            const size_t kbase = (size_t)((b * NN + tok0) >> 4) * 2560 + lane * 8;
            floatx4 a0[3] = {{0,0,0,0},{0,0,0,0},{0,0,0,0}};
            floatx4 a1[3] = {{0,0,0,0},{0,0,0,0},{0,0,0,0}};
            #pragma unroll
            for (int ks = 0; ks < 5; ks++) {
                short8 bh = *(const short8*)&khp[kbase + ks * 512];
                short8 bl = *(const short8*)&klp[kbase + ks * 512];
                a0[0] = __builtin_amdgcn_mfma_f32_16x16x32_bf16(aqh[0][ks], bh, a0[0], 0, 0, 0);
                a0[1] = __builtin_amdgcn_mfma_f32_16x16x32_bf16(aql[0][ks], bh, a0[1], 0, 0, 0);
                a0[2] = __builtin_amdgcn_mfma_f32_16x16x32_bf16(aqh[0][ks], bl, a0[2], 0, 0, 0);
                a1[0] = __builtin_amdgcn_mfma_f32_16x16x32_bf16(aqh[1][ks], bh, a1[0], 0, 0, 0);
                a1[1] = __builtin_amdgcn_mfma_f32_16x16x32_bf16(aql[1][ks], bh, a1[1], 0, 0, 0);
                a1[2] = __builtin_amdgcn_mfma_f32_16x16x32_bf16(aqh[1][ks], bl, a1[2], 0, 0, 0);
            }
            // frag-major P address parts for this tok
            const size_t tbase = (size_t)(tok >> 5) * 512 + ((tok >> 3) & 3) * 128 + (tok & 7);
            #pragma unroll
            for (int r = 0; r < 4; r++) {
                float e0 = a0[0][r] + a0[1][r] + a0[2][r];
                float e1 = a1[0][r] + a1[1][r] + a1[2][r];
                float p0 = __expf(e0 - SHIFT);
                float p1 = __expf(e1 - SHIFT);
                Pb[tbase + (l4 * 4 + r) * 8] = f2bf(p0);           // rows i0..i0+15
                Pb[tbase + (l4 * 4 + r) * 8 + 32768] = f2bf(p1);   // rows i0+16..i0+31
                sr[0][r] += p0;
                sr[1][r] += p1;
            }
        }
    }

    #pragma unroll
    for (int rt = 0; rt < 2; rt++)
        #pragma unroll
        for (int r = 0; r < 4; r++) {
            float v = sr[rt][r];
            v += __shfl_xor(v, 1);
            v += __shfl_xor(v, 2);
            v += __shfl_xor(v, 4);
            v += __shfl_xor(v, 8);
            if (l15 == 0) sums[wave][rt * 16 + l4 * 4 + r] = v;
        }
    __syncthreads();
    if (tid < 32)
        Lsum[(size_t)b * NN + i0 + tid] =
            sums[0][tid] + sums[1][tid] + sums[2][tid] + sums[3][tid];
}

// ---------------- Kernel 2b v8: 256x160 frag-major pipeline GEMM ----------------
// v7 diagnosis: LDS unit ~95% busy (48 KB traffic per 64-MFMA block-step) ->
// MfmaUtil capped ~42%. v8 cuts LDS bytes/MFMA: 256x160 tile, 512 threads,
// 8 waves (4M x 2N, wave = 64x80, acc[4][5]): 160 MFMA per 98 KB LDS traffic
// (2.22 MFMA/KB vs 2.0). Grid: 8b x 8m x 8n = 512 blocks = EXACTLY 2 rounds
// at 2 blocks/CU (no tail). Depth-2, 2-slot (52 KB) counted-vmcnt pipeline;
// frag-major linear gload_lds staging (0 conflicts, proven v7 machinery).
// Staging: 1664 granules/tile; threads do 3 each, waves 0-1 a 4th ->
// per-wave counted vmcnt(4)/vmcnt(3) (wave-uniform branch).
#define PV_SLOT_SH 13312   // shorts per slot: A 8192 + B 5120

__global__ __launch_bounds__(512, 4) void pv_gemm(
    const unsigned short* __restrict__ P, const unsigned short* __restrict__ vt,
    const float* __restrict__ Lsum,
    const float* __restrict__ x, float* __restrict__ out)
{
    __shared__ __align__(16) unsigned short Sm[2 * PV_SLOT_SH];   // 52 KiB

    const int p0 = blockIdx.x;          // 0..511
    const int b  = p0 & 7;              // one batch per XCD
    const int t  = p0 >> 3;             // 0..63
    const int m0 = (t >> 3) * 256;
    const int n0 = (t & 7) * 160;

    const int tid = threadIdx.x;
    const int wave = tid >> 6, lane = tid & 63;
    const int l15 = lane & 15, l4 = lane >> 4;
    const int wm = wave >> 1, wn = wave & 1;    // 4M x 2N

    const unsigned short* PbF = P  + (size_t)b * NN * NN + (size_t)(m0 >> 4) * 32768;
    const unsigned short* VbF = vt + (size_t)b * LL * NN + (size_t)(n0 >> 4) * 32768;

    // per-thread staging granules: p = i*512+tid (i=0..2); waves 0-1: p3=1536+tid
    // p < 1024 -> A granule p; else B granule p-1024.
    const unsigned short* gsrc[4];
    unsigned dofs[4];
    #pragma unroll
    for (int i = 0; i < 3; i++) {
        int p = i * 512 + tid;
        dofs[i] = (unsigned)p * 8;
        if (p < 1024)
            gsrc[i] = PbF + (unsigned)(p >> 6) * 32768u + (p & 63) * 8;
        else {
            int q = p - 1024;
            gsrc[i] = VbF + (unsigned)(q >> 6) * 32768u + (q & 63) * 8;
        }
    }
    {
        int p = 1536 + tid;            // only used by waves 0-1 (tid<128)
        int q = p - 1024;
        dofs[3] = (unsigned)p * 8;
        gsrc[3] = VbF + (unsigned)(q >> 6) * 32768u + (q & 63) * 8;
    }

    floatx4 acc[4][5] = {};

    auto STAGE = [&](int slot, int ks) {
        unsigned short* S = Sm + slot * PV_SLOT_SH;
        const unsigned ko = (unsigned)ks * 512u;
        gl16(gsrc[0] + ko, S + dofs[0]);
        gl16(gsrc[1] + ko, S + dofs[1]);
        gl16(gsrc[2] + ko, S + dofs[2]);
        if (tid < 128)
            gl16(gsrc[3] + ko, S + dofs[3]);
    };

    auto COMPUTE = [&](int slot) {
        const unsigned short* A  = Sm + slot * PV_SLOT_SH;
        const unsigned short* Bs = A + 8192;
        short8 a[4];
        #pragma unroll
        for (int mf = 0; mf < 4; mf++)
            a[mf] = *(const short8*)(A + ((wm * 4 + mf) * 64 + lane) * 8);
        __builtin_amdgcn_s_setprio(1);
        #pragma unroll
        for (int nf = 0; nf < 5; nf++) {
            short8 bb = *(const short8*)(Bs + ((wn * 5 + nf) * 64 + lane) * 8);
            #pragma unroll
            for (int mf = 0; mf < 4; mf++)
                acc[mf][nf] = __builtin_amdgcn_mfma_f32_16x16x32_bf16(a[mf], bb, acc[mf][nf], 0, 0, 0);
        }
        __builtin_amdgcn_s_setprio(0);
    };

    STAGE(0, 0); STAGE(1, 1);           // depth-2 prologue

    for (int kt = 0; kt < 62; ++kt) {
        if (wave < 2) asm volatile("s_waitcnt vmcnt(4)" ::: "memory");
        else          asm volatile("s_waitcnt vmcnt(3)" ::: "memory");
        asm volatile("s_barrier" ::: "memory");     // all waves' tile-kt loads visible
        COMPUTE(kt & 1);
        asm volatile("s_barrier" ::: "memory");     // slot free for reuse
        STAGE(kt & 1, kt + 2);
    }
    // tiles 62, 63
    if (wave < 2) asm volatile("s_waitcnt vmcnt(4)" ::: "memory");
    else          asm volatile("s_waitcnt vmcnt(3)" ::: "memory");
    asm volatile("s_barrier" ::: "memory");
    COMPUTE(0);
    asm volatile("s_waitcnt vmcnt(0)" ::: "memory");
    asm volatile("s_barrier" ::: "memory");
    COMPUTE(1);

    float linv[4][4];
    #pragma unroll
    for (int mf = 0; mf < 4; mf++)
        #pragma unroll
        for (int r = 0; r < 4; r++)
            linv[mf][r] = 1.0f / Lsum[(size_t)b * NN + m0 + wm * 64 + mf * 16 + l4 * 4 + r];

    #pragma unroll
    for (int mf = 0; mf < 4; mf++)
        #pragma unroll
        for (int nf = 0; nf < 5; nf++)
            #pragma unroll
            for (int r = 0; r < 4; r++) {
                int row = m0 + wm * 64 + mf * 16 + l4 * 4 + r;
                int col = n0 + wn * 80 + nf * 16 + l15;
                size_t idx = ((size_t)b * NN + row) * LL + col;
                out[idx] = acc[mf][nf][r] * linv[mf][r] + x[idx];
            }
}

extern "C" void kernel_launch(void* const* d_in, const int* in_sizes, int n_in,
                              void* d_out, int out_size, void* d_ws, size_t ws_size,
                              hipStream_t stream) {
    const float* x  = (const float*)d_in[0];
    const float* Wq = (const float*)d_in[1];
    const float* bq = (const float*)d_in[2];
    const float* Wk = (const float*)d_in[3];
    const float* bk = (const float*)d_in[4];
    const float* Wv = (const float*)d_in[5];
    const float* bv = (const float*)d_in[6];
    float* out = (float*)d_out;

    // ws layout (~135 MB)
    unsigned short* wqk_h = (unsigned short*)d_ws;            // [20 o16][20480] frag-major
    unsigned short* wqk_l = wqk_h + (size_t)2*HH * LL;
    unsigned short* wv    = wqk_l + (size_t)2*HH * LL;        // [LL*LL] frag-major
    unsigned short* qh    = wv    + (size_t)LL * LL;          // [BN][HH] frag-major
    unsigned short* ql    = qh    + (size_t)BN * HH;
    unsigned short* kh    = ql    + (size_t)BN * HH;
    unsigned short* kl    = kh    + (size_t)BN * HH;
    unsigned short* vt    = kl    + (size_t)BN * HH;          // [BB][LL*NN] frag-major
    unsigned short* P     = vt    + (size_t)BB * LL * NN;     // [BB][NN*NN] frag-major
    float*          Lsum  = (float*)(P + (size_t)BB * NN * NN); // [BN]
    // Aliases (sequential-stream ordering makes these safe):
    //   xh (42 MB) aliases P (67 MB): consumed by proj_qk + proj_v, both
    //     complete before s_exp writes P.
    //   xl (42 MB) aliases vt (42 MB, exact fit): consumed only by proj_qk,
    //     which completes before proj_v writes vt.
    unsigned short* xh    = P;
    unsigned short* xl    = vt;

    cast_w<<<dim3(NO), dim3(256), 0, stream>>>(Wq, Wk, Wv, wqk_h, wqk_l, wv);

    cast_x<<<dim3(BN / 16), dim3(256), 0, stream>>>(x, xh, xl);

    // 512 blocks (2/CU), 4 waves: block = 32 rows x all 320 outputs
    proj_qk<<<dim3(BN / 32), dim3(256), 0, stream>>>(
        xh, xl, wqk_h, wqk_l, bq, bk, qh, ql, kh, kl);

    // flat 1280 blocks: xcd = bid&7 owns batch xcd; f-fastest within XCD
    proj_v<<<dim3(1280), dim3(256), 0, stream>>>(xh, wv, bv, vt);

    dim3 gs(NN / 32, BB);                  // (64, 8)
    s_exp<<<gs, dim3(256), 0, stream>>>(qh, ql, kh, kl, P, Lsum);

    // 512 blocks of 512 threads: b = bid&7 (batch per XCD), 8m x 8n tiles
    pv_gemm<<<dim3(512), dim3(512), 0, stream>>>(P, vt, Lsum, x, out);
}

// Round 12
// 428.055 us; speedup vs baseline: 1.0833x; 1.0833x over previous
//
#include <hip/hip_runtime.h>

#define BB 8
#define NN 2048
#define LL 1280
#define HH 160
#define BN (BB*NN)          // 16384
#define NO (2*HH + LL)      // 1600
#define SHIFT 40.0f

typedef __attribute__((ext_vector_type(8))) short short8;
typedef __attribute__((ext_vector_type(4))) float floatx4;

__device__ __forceinline__ unsigned short f2bf(float f) {
    unsigned int u = __builtin_bit_cast(unsigned int, f);
    u = (u + 0x7FFFu + ((u >> 16) & 1u)) >> 16;
    return (unsigned short)u;
}
__device__ __forceinline__ float bf2f(unsigned short h) {
    unsigned int u = ((unsigned int)h) << 16;
    return __builtin_bit_cast(float, u);
}
__device__ __forceinline__ void split2(float f, unsigned short& hi, unsigned short& lo) {
    hi = f2bf(f);
    lo = f2bf(f - bf2f(hi));
}

// Fragment-major layouts (MFMA-native, lane = ((k>>3)&3)*16 + (row&15)):
//   q/k:  F(m,h)   = (m>>4)*2560  + (h>>5)*512   + ((h>>3)&3)*128 + (m&15)*8 + (h&7)
//   P:    F(r,tok) = (r>>4)*32768 + (tok>>5)*512 + ((tok>>3)&3)*128 + (r&15)*8 + (tok&7)
//   vt:   F(f,tok) = (f>>4)*32768 + (tok>>5)*512 + ((tok>>3)&3)*128 + (f&15)*8 + (tok&7)
//   xh/xl:F(m,k)   = (m>>4)*20480 + (k>>5)*512   + ((k>>3)&3)*128 + (m&15)*8 + (k&7)
//   wv:   F(f,k)   = (f>>4)*20480 + (k>>5)*512   + ((k>>3)&3)*128 + (f&15)*8 + (k&7)
//   wqk:  F(o,k)   = (o>>4)*20480 + (k>>5)*512   + ((k>>3)&3)*128 + (o&15)*8 + (k&7)
// A 16-row x 32-k fragment = one contiguous 1KB wave-load / gload_lds chunk.

__device__ __forceinline__ void gl16(const unsigned short* g, unsigned short* l) {
    __builtin_amdgcn_global_load_lds(
        (const __attribute__((address_space(1))) unsigned int*)g,
        (__attribute__((address_space(3))) unsigned int*)l, 16, 0, 0);
}

// ---------------- cast weights (wqk + wv frag-major) ----------------
__global__ __launch_bounds__(256) void cast_w(
    const float* __restrict__ Wq, const float* __restrict__ Wk, const float* __restrict__ Wv,
    unsigned short* __restrict__ wqk_h, unsigned short* __restrict__ wqk_l,
    unsigned short* __restrict__ wv)
{
    int o = blockIdx.x;   // 0..1599
    if (o < 2*HH) {
        const float* src = (o < HH) ? (Wq + (size_t)o * LL) : (Wk + (size_t)(o - HH) * LL);
        unsigned short* dh = wqk_h + (size_t)(o >> 4) * 20480 + (o & 15) * 8;
        unsigned short* dl = wqk_l + (size_t)(o >> 4) * 20480 + (o & 15) * 8;
        for (int c = threadIdx.x; c < LL; c += 256) {
            unsigned short h, l;
            split2(src[c], h, l);
            unsigned off = (unsigned)(c >> 5) * 512 + ((c >> 3) & 3) * 128 + (c & 7);
            dh[off] = h; dl[off] = l;
        }
    } else {
        // wv frag-major
        int f = o - 2*HH;
        const float* src = Wv + (size_t)f * LL;
        unsigned short* dstF = wv + (size_t)(f >> 4) * 20480 + (f & 15) * 8;
        for (int c = threadIdx.x * 4; c < LL; c += 256 * 4) {
            float4 v = *(const float4*)(src + c);
            ushort4 u;
            u.x = f2bf(v.x); u.y = f2bf(v.y); u.z = f2bf(v.z); u.w = f2bf(v.w);
            *(ushort4*)(dstF + (size_t)(c >> 5) * 512 + ((c >> 3) & 3) * 128 + (c & 7)) = u;
        }
    }
}

// ---------------- cast x -> bf16x2 (hi+lo) frag-major ----------------
__global__ __launch_bounds__(256) void cast_x(
    const float* __restrict__ x,
    unsigned short* __restrict__ xh, unsigned short* __restrict__ xl)
{
    const int g   = blockIdx.x;              // m16 group 0..1023
    const int tid = threadIdx.x;
    const float* src = x + (size_t)(g * 16 + (tid & 15)) * LL + ((tid >> 4) & 3) * 8;
    unsigned short* dsth = xh + (size_t)g * 20480 + tid * 8;
    unsigned short* dstl = xl + (size_t)g * 20480 + tid * 8;
    const int ks0 = tid >> 6;                // 0..3
    #pragma unroll
    for (int it = 0; it < 10; it++) {
        int k0 = (it * 4 + ks0) * 32;
        float4 f0 = *(const float4*)(src + k0);
        float4 f1 = *(const float4*)(src + k0 + 4);
        float fv[8] = {f0.x, f0.y, f0.z, f0.w, f1.x, f1.y, f1.z, f1.w};
        short8 h8, l8;
        #pragma unroll
        for (int i = 0; i < 8; i++) {
            unsigned short hh, lll;
            split2(fv[i], hh, lll);
            h8[i] = (short)hh; l8[i] = (short)lll;
        }
        *(short8*)(dsth + it * 2048) = h8;
        *(short8*)(dstl + it * 2048) = l8;
    }
}

// ---------------- Kernel 1a v3: q,k projection, direct-frag stream ----------------
__global__ __launch_bounds__(256, 2) void proj_qk(
    const unsigned short* __restrict__ xh, const unsigned short* __restrict__ xl,
    const unsigned short* __restrict__ wh, const unsigned short* __restrict__ wl,
    const float* __restrict__ bq, const float* __restrict__ bk,
    unsigned short* __restrict__ qh, unsigned short* __restrict__ ql,
    unsigned short* __restrict__ kh, unsigned short* __restrict__ kl)
{
    const int mg0 = blockIdx.x * 2;       // m16 group base (32 rows)
    const int tid = threadIdx.x;
    const int wave = tid >> 6, lane = tid & 63;
    const int l15 = lane & 15, l4 = lane >> 4;

    const unsigned aBase = (unsigned)mg0 * 20480u + lane * 8;
    const unsigned bBase = (unsigned)(wave * 5) * 20480u + lane * 8;

    floatx4 acc[2][5] = {};

    #pragma unroll 2
    for (int ks = 0; ks < 40; ks++) {
        const unsigned ko = (unsigned)ks * 512u;
        short8 ah[2], al[2], bh[5], bl[5];
        #pragma unroll
        for (int mf = 0; mf < 2; mf++) {
            ah[mf] = *(const short8*)(xh + aBase + mf * 20480u + ko);
            al[mf] = *(const short8*)(xl + aBase + mf * 20480u + ko);
        }
        #pragma unroll
        for (int nf = 0; nf < 5; nf++) {
            bh[nf] = *(const short8*)(wh + bBase + nf * 20480u + ko);
            bl[nf] = *(const short8*)(wl + bBase + nf * 20480u + ko);
        }
        #pragma unroll
        for (int mf = 0; mf < 2; mf++)
            #pragma unroll
            for (int nf = 0; nf < 5; nf++) {
                acc[mf][nf] = __builtin_amdgcn_mfma_f32_16x16x32_bf16(ah[mf], bh[nf], acc[mf][nf], 0, 0, 0);
                acc[mf][nf] = __builtin_amdgcn_mfma_f32_16x16x32_bf16(al[mf], bh[nf], acc[mf][nf], 0, 0, 0);
                acc[mf][nf] = __builtin_amdgcn_mfma_f32_16x16x32_bf16(ah[mf], bl[nf], acc[mf][nf], 0, 0, 0);
            }
    }

    // epilogue: bias + bf16x2 split + frag-major q/k stores
    #pragma unroll
    for (int nf = 0; nf < 5; nf++) {
        int o = wave * 80 + nf * 16 + l15;
        bool isQ = (o < HH);
        float bias = isQ ? bq[o] : bk[o - HH];
        int oo = isQ ? o : (o - HH);
        unsigned short* dh = isQ ? qh : kh;
        unsigned short* dl = isQ ? ql : kl;
        unsigned ob = (unsigned)(oo >> 5) * 512u + ((oo >> 3) & 3) * 128u + (oo & 7);
        #pragma unroll
        for (int mf = 0; mf < 2; mf++) {
            unsigned fa0 = (unsigned)(mg0 + mf) * 2560u + ob + (l4 * 4) * 8u;
            #pragma unroll
            for (int r = 0; r < 4; r++) {
                float val = acc[mf][nf][r] + bias;
                unsigned short vh, vl;
                split2(val, vh, vl);
                dh[fa0 + r * 8] = vh;
                dl[fa0 + r * 8] = vl;
            }
        }
    }
}

// ---------------- Kernel 1b v2: v projection, v7 quadrant pipeline ----------------
__global__ __launch_bounds__(256, 3) void proj_v(
    const unsigned short* __restrict__ xh, const unsigned short* __restrict__ wv,
    const float* __restrict__ bv, unsigned short* __restrict__ vt)
{
    __shared__ __align__(16) unsigned short Sm[3 * 8192];   // 48 KiB

    const int bid = blockIdx.x;         // 0..1279
    const int xcd = bid & 7;
    const int q   = bid >> 3;           // 0..159
    const int mt  = xcd * 16 + q / 10;  // m-tile 0..127 (batch = xcd)
    const int ft  = q % 10;             // f-tile 0..9
    const int m0 = mt * 128;
    const int f0 = ft * 128;

    const int tid = threadIdx.x;
    const int wave = tid >> 6, lane = tid & 63;
    const int l15 = lane & 15, l4 = lane >> 4;
    const int wm = wave >> 1, wn = wave & 1;

    const unsigned short* AF = xh + (size_t)(m0 >> 4) * 20480;
    const unsigned short* BF = wv + (size_t)(f0 >> 4) * 20480;

    const int sp0 = tid, sp1 = 256 + tid;
    const unsigned sa0 = (unsigned)(sp0 >> 6) * 20480u + (sp0 & 63) * 8;
    const unsigned sa1 = (unsigned)(sp1 >> 6) * 20480u + (sp1 & 63) * 8;

    floatx4 acc[4][4] = {};

    auto STAGE = [&](int slot, int ks) {
        unsigned short* A  = Sm + slot * 8192;
        unsigned short* Bs = A + 4096;
        const unsigned ko = (unsigned)ks * 512u;
        gl16(AF + sa0 + ko, A  + sp0 * 8);
        gl16(BF + sa0 + ko, Bs + sp0 * 8);
        gl16(AF + sa1 + ko, A  + sp1 * 8);
        gl16(BF + sa1 + ko, Bs + sp1 * 8);
    };

    auto COMPUTE = [&](int slot) {
        const unsigned short* A  = Sm + slot * 8192;
        const unsigned short* Bs = A + 4096;
        short8 a[4], bb[4];
        #pragma unroll
        for (int mf = 0; mf < 4; mf++)
            a[mf] = *(const short8*)(A + ((wm * 4 + mf) * 64 + lane) * 8);
        #pragma unroll
        for (int nf = 0; nf < 4; nf++)
            bb[nf] = *(const short8*)(Bs + ((wn * 4 + nf) * 64 + lane) * 8);
        __builtin_amdgcn_s_setprio(1);
        #pragma unroll
        for (int mf = 0; mf < 4; mf++)
            #pragma unroll
            for (int nf = 0; nf < 4; nf++)
                acc[mf][nf] = __builtin_amdgcn_mfma_f32_16x16x32_bf16(a[mf], bb[nf], acc[mf][nf], 0, 0, 0);
        __builtin_amdgcn_s_setprio(0);
    };

    STAGE(0, 0); STAGE(1, 1); STAGE(2, 2);

    int s = 0;
    for (int kt = 0; kt < 37; ++kt) {              // 40 K-steps total
        asm volatile("s_waitcnt vmcnt(8)" ::: "memory");
        asm volatile("s_barrier" ::: "memory");
        COMPUTE(s);
        asm volatile("s_barrier" ::: "memory");
        STAGE(s, kt + 3);
        s = (s == 2) ? 0 : s + 1;
    }
    asm volatile("s_waitcnt vmcnt(8)" ::: "memory");
    asm volatile("s_barrier" ::: "memory");
    COMPUTE(s); s = (s == 2) ? 0 : s + 1;
    asm volatile("s_waitcnt vmcnt(4)" ::: "memory");
    asm volatile("s_barrier" ::: "memory");
    COMPUTE(s); s = (s == 2) ? 0 : s + 1;
    asm volatile("s_waitcnt vmcnt(0)" ::: "memory");
    asm volatile("s_barrier" ::: "memory");
    COMPUTE(s);

    // epilogue: bias + direct frag-major vt stores (ushort4 over r)
    const int b    = m0 >> 11;                    // == xcd
    const int tokb = (m0 & 2047) + wm * 64;
    unsigned short* vtB = vt + (size_t)b * LL * NN;
    float bvv[4];
    #pragma unroll
    for (int nf = 0; nf < 4; nf++)
        bvv[nf] = bv[f0 + wn * 64 + nf * 16 + l15];

    #pragma unroll
    for (int mf = 0; mf < 4; mf++)
        #pragma unroll
        for (int nf = 0; nf < 4; nf++) {
            int f   = f0 + wn * 64 + nf * 16 + l15;
            int tok = tokb + mf * 16 + l4 * 4;    // +r, r=0..3 contiguous in (tok&7)
            ushort4 u;
            u.x = f2bf(acc[mf][nf][0] + bvv[nf]);
            u.y = f2bf(acc[mf][nf][1] + bvv[nf]);
            u.z = f2bf(acc[mf][nf][2] + bvv[nf]);
            u.w = f2bf(acc[mf][nf][3] + bvv[nf]);
            *(ushort4*)(vtB + (size_t)(f >> 4) * 32768 + (tok >> 5) * 512
                        + ((tok >> 3) & 3) * 128 + (f & 15) * 8 + (tok & 7)) = u;
        }
}

// ---------------- Kernel 2a v2: S = exp(QK^T - SHIFT), 64-row blocks ----------------
// Diagnosis: old s_exp was L2-BW-bound (10 KB B-frags per 30 MFMA ≈ 276
// B/cyc/CU demand vs ~56 L2 share). v2 doubles B-reuse: 64 rows resident
// per block (4 rowtiles x 5 ks hi+lo = 160 VGPR), 512 threads / 8 waves
// j-split, single accumulator per rowtile (3 precision chains fold into one
// acc — 4 rowtile chains give sufficient MFMA ILP), 60 MFMA per 10 KB.
// Grid flat 256 = 1 block/CU, b = bid&7 -> batch per XCD (K-panel HBM
// fetch once per XCD). L2 read traffic halves: 1.34 GB -> 0.67 GB.
__global__ __launch_bounds__(512, 2) void s_exp(
    const unsigned short* __restrict__ qhp, const unsigned short* __restrict__ qlp,
    const unsigned short* __restrict__ khp, const unsigned short* __restrict__ klp,
    unsigned short* __restrict__ P, float* __restrict__ Lsum)
{
    __shared__ float sums[8][64];
    const int bid = blockIdx.x;        // 0..255
    const int b   = bid & 7;           // one batch per XCD
    const int i0  = (bid >> 3) * 64;   // 64 q-rows
    const int tid = threadIdx.x;
    const int wave = tid >> 6, lane = tid & 63;
    const int l15 = lane & 15, l4 = lane >> 4;

    // resident A-frags: 4 rowtiles x 5 ks, hi+lo (160 VGPR)
    short8 aqh[4][5], aql[4][5];
    #pragma unroll
    for (int rt = 0; rt < 4; rt++) {
        const size_t rowb = (size_t)((b * NN + i0 + rt * 16) >> 4) * 2560 + lane * 8;
        #pragma unroll
        for (int ks = 0; ks < 5; ks++) {
            aqh[rt][ks] = *(const short8*)&qhp[rowb + ks * 512];
            aql[rt][ks] = *(const short8*)&qlp[rowb + ks * 512];
        }
    }

    float sr[4][4] = {};
    unsigned short* Pb = P + (size_t)b * NN * NN + (size_t)(i0 >> 4) * 32768;

    for (int c0 = 0; c0 < NN; c0 += 512) {
        const int jb = c0 + wave * 64;      // wave's 64-col stripe
        #pragma unroll
        for (int ct = 0; ct < 4; ct++) {
            const int tok0 = jb + ct * 16;                 // multiple of 16
            const int tok  = tok0 + l15;
            const size_t kbase = (size_t)((b * NN + tok0) >> 4) * 2560 + lane * 8;
            floatx4 a[4] = {{0,0,0,0},{0,0,0,0},{0,0,0,0},{0,0,0,0}};
            #pragma unroll
            for (int ks = 0; ks < 5; ks++) {
                short8 bh = *(const short8*)&khp[kbase + ks * 512];
                short8 bl = *(const short8*)&klp[kbase + ks * 512];
                #pragma unroll
                for (int rt = 0; rt < 4; rt++) {
                    a[rt] = __builtin_amdgcn_mfma_f32_16x16x32_bf16(aqh[rt][ks], bh, a[rt], 0, 0, 0);
                    a[rt] = __builtin_amdgcn_mfma_f32_16x16x32_bf16(aql[rt][ks], bh, a[rt], 0, 0, 0);
                    a[rt] = __builtin_amdgcn_mfma_f32_16x16x32_bf16(aqh[rt][ks], bl, a[rt], 0, 0, 0);
                }
            }
            const size_t tbase = (size_t)(tok >> 5) * 512 + ((tok >> 3) & 3) * 128 + (tok & 7);
            #pragma unroll
            for (int rt = 0; rt < 4; rt++)
                #pragma unroll
                for (int r = 0; r < 4; r++) {
                    float p = __expf(a[rt][r] - SHIFT);
                    Pb[tbase + (size_t)rt * 32768 + (l4 * 4 + r) * 8] = f2bf(p);
                    sr[rt][r] += p;
                }
        }
    }

    // reduce row sums over l15 (16 lanes), then across the 8 waves via LDS
    #pragma unroll
    for (int rt = 0; rt < 4; rt++)
        #pragma unroll
        for (int r = 0; r < 4; r++) {
            float v = sr[rt][r];
            v += __shfl_xor(v, 1);
            v += __shfl_xor(v, 2);
            v += __shfl_xor(v, 4);
            v += __shfl_xor(v, 8);
            if (l15 == 0) sums[wave][rt * 16 + l4 * 4 + r] = v;
        }
    __syncthreads();
    if (tid < 64) {
        float s = 0.f;
        #pragma unroll
        for (int w = 0; w < 8; w++) s += sums[w][tid];
        Lsum[(size_t)b * NN + i0 + tid] = s;
    }
}

// ---------------- Kernel 2b v7 (reverted): frag-major quadrant GEMM ----------------
// v8 (256x160, depth-2) regressed 99->128 us: depth-2 gives ~1 compute-step
// of slack vs ~900cy HBM latency, and 8-wave barriers cost more. v7's
// depth-3 + 3 blocks/CU is the measured optimum (99 us, MfmaUtil 38%).
__global__ __launch_bounds__(256, 3) void pv_gemm(
    const unsigned short* __restrict__ P, const unsigned short* __restrict__ vt,
    const float* __restrict__ Lsum,
    const float* __restrict__ x, float* __restrict__ out)
{
    __shared__ __align__(16) unsigned short Sm[3 * 8192];   // 48 KiB

    const int p0 = blockIdx.x;          // 0..1279
    const int b  = p0 & 7;              // one batch per XCD
    const int t  = p0 >> 3;             // 0..159
    const int n0 = (t % 10) * 128;
    const int m0 = (t / 10) * 128;

    const int tid = threadIdx.x;
    const int wave = tid >> 6, lane = tid & 63;
    const int l15 = lane & 15, l4 = lane >> 4;
    const int wm = wave >> 1, wn = wave & 1;

    const unsigned short* PbF = P  + (size_t)b * NN * NN + (size_t)(m0 >> 4) * 32768;
    const unsigned short* VbF = vt + (size_t)b * LL * NN + (size_t)(n0 >> 4) * 32768;

    const int sp0 = tid, sp1 = 256 + tid;
    const unsigned sa0 = (unsigned)(sp0 >> 6) * 32768u + (sp0 & 63) * 8;
    const unsigned sa1 = (unsigned)(sp1 >> 6) * 32768u + (sp1 & 63) * 8;

    floatx4 acc[4][4] = {};

    auto STAGE = [&](int slot, int ks) {
        unsigned short* A  = Sm + slot * 8192;
        unsigned short* Bs = A + 4096;
        const unsigned ko = (unsigned)ks * 512u;
        gl16(PbF + sa0 + ko, A  + sp0 * 8);
        gl16(VbF + sa0 + ko, Bs + sp0 * 8);
        gl16(PbF + sa1 + ko, A  + sp1 * 8);
        gl16(VbF + sa1 + ko, Bs + sp1 * 8);
    };

    auto COMPUTE = [&](int slot) {
        const unsigned short* A  = Sm + slot * 8192;
        const unsigned short* Bs = A + 4096;
        short8 a[4], bb[4];
        #pragma unroll
        for (int mf = 0; mf < 4; mf++)
            a[mf] = *(const short8*)(A + ((wm * 4 + mf) * 64 + lane) * 8);
        #pragma unroll
        for (int nf = 0; nf < 4; nf++)
            bb[nf] = *(const short8*)(Bs + ((wn * 4 + nf) * 64 + lane) * 8);
        __builtin_amdgcn_s_setprio(1);
        #pragma unroll
        for (int mf = 0; mf < 4; mf++)
            #pragma unroll
            for (int nf = 0; nf < 4; nf++)
                acc[mf][nf] = __builtin_amdgcn_mfma_f32_16x16x32_bf16(a[mf], bb[nf], acc[mf][nf], 0, 0, 0);
        __builtin_amdgcn_s_setprio(0);
    };

    STAGE(0, 0); STAGE(1, 1); STAGE(2, 2);

    int s = 0;
    for (int kt = 0; kt < 61; ++kt) {
        asm volatile("s_waitcnt vmcnt(8)" ::: "memory");
        asm volatile("s_barrier" ::: "memory");
        COMPUTE(s);
        asm volatile("s_barrier" ::: "memory");
        STAGE(s, kt + 3);
        s = (s == 2) ? 0 : s + 1;
    }
    asm volatile("s_waitcnt vmcnt(8)" ::: "memory");
    asm volatile("s_barrier" ::: "memory");
    COMPUTE(s); s = (s == 2) ? 0 : s + 1;
    asm volatile("s_waitcnt vmcnt(4)" ::: "memory");
    asm volatile("s_barrier" ::: "memory");
    COMPUTE(s); s = (s == 2) ? 0 : s + 1;
    asm volatile("s_waitcnt vmcnt(0)" ::: "memory");
    asm volatile("s_barrier" ::: "memory");
    COMPUTE(s);

    float linv[4][4];
    #pragma unroll
    for (int mf = 0; mf < 4; mf++)
        #pragma unroll
        for (int r = 0; r < 4; r++)
            linv[mf][r] = 1.0f / Lsum[(size_t)b * NN + m0 + wm * 64 + mf * 16 + l4 * 4 + r];

    #pragma unroll
    for (int mf = 0; mf < 4; mf++)
        #pragma unroll
        for (int nf = 0; nf < 4; nf++)
            #pragma unroll
            for (int r = 0; r < 4; r++) {
                int row = m0 + wm * 64 + mf * 16 + l4 * 4 + r;
                int col = n0 + wn * 64 + nf * 16 + l15;
                size_t idx = ((size_t)b * NN + row) * LL + col;
                out[idx] = acc[mf][nf][r] * linv[mf][r] + x[idx];
            }
}

extern "C" void kernel_launch(void* const* d_in, const int* in_sizes, int n_in,
                              void* d_out, int out_size, void* d_ws, size_t ws_size,
                              hipStream_t stream) {
    const float* x  = (const float*)d_in[0];
    const float* Wq = (const float*)d_in[1];
    const float* bq = (const float*)d_in[2];
    const float* Wk = (const float*)d_in[3];
    const float* bk = (const float*)d_in[4];
    const float* Wv = (const float*)d_in[5];
    const float* bv = (const float*)d_in[6];
    float* out = (float*)d_out;

    // ws layout (~135 MB)
    unsigned short* wqk_h = (unsigned short*)d_ws;            // [20 o16][20480] frag-major
    unsigned short* wqk_l = wqk_h + (size_t)2*HH * LL;
    unsigned short* wv    = wqk_l + (size_t)2*HH * LL;        // [LL*LL] frag-major
    unsigned short* qh    = wv    + (size_t)LL * LL;          // [BN][HH] frag-major
    unsigned short* ql    = qh    + (size_t)BN * HH;
    unsigned short* kh    = ql    + (size_t)BN * HH;
    unsigned short* kl    = kh    + (size_t)BN * HH;
    unsigned short* vt    = kl    + (size_t)BN * HH;          // [BB][LL*NN] frag-major
    unsigned short* P     = vt    + (size_t)BB * LL * NN;     // [BB][NN*NN] frag-major
    float*          Lsum  = (float*)(P + (size_t)BB * NN * NN); // [BN]
    // Aliases (sequential-stream ordering makes these safe):
    //   xh (42 MB) aliases P (67 MB): consumed by proj_qk + proj_v, both
    //     complete before s_exp writes P.
    //   xl (42 MB) aliases vt (42 MB, exact fit): consumed only by proj_qk,
    //     which completes before proj_v writes vt.
    unsigned short* xh    = P;
    unsigned short* xl    = vt;

    cast_w<<<dim3(NO), dim3(256), 0, stream>>>(Wq, Wk, Wv, wqk_h, wqk_l, wv);

    cast_x<<<dim3(BN / 16), dim3(256), 0, stream>>>(x, xh, xl);

    // 512 blocks (2/CU), 4 waves: block = 32 rows x all 320 outputs
    proj_qk<<<dim3(BN / 32), dim3(256), 0, stream>>>(
        xh, xl, wqk_h, wqk_l, bq, bk, qh, ql, kh, kl);

    // flat 1280 blocks: xcd = bid&7 owns batch xcd; f-fastest within XCD
    proj_v<<<dim3(1280), dim3(256), 0, stream>>>(xh, wv, bv, vt);

    // flat 256 blocks of 512 threads: b = bid&7 (batch per XCD), 64 rows each
    s_exp<<<dim3(256), dim3(512), 0, stream>>>(qh, ql, kh, kl, P, Lsum);

    // flat 1280 blocks: b = bid&7 (batch per XCD), t = bid>>3 -> (n,m) tile
    pv_gemm<<<dim3(1280), dim3(256), 0, stream>>>(P, vt, Lsum, x, out);
}